// Round 2
// baseline (3524985.938 us; speedup 1.0000x reference)
//
#include <hip/hip_runtime.h>

typedef __attribute__((ext_vector_type(8))) short short8;
typedef __attribute__((ext_vector_type(4))) float floatx4;
typedef __attribute__((ext_vector_type(4))) unsigned short ushortx4;
typedef __attribute__((ext_vector_type(8))) unsigned short ushortx8;
typedef unsigned int u32;
typedef __attribute__((ext_vector_type(2))) u32 u32x2;
typedef __attribute__((ext_vector_type(4))) u32 u32x4;

#define MFMA_K32(A, B, C) __builtin_amdgcn_mfma_f32_16x16x32_bf16(A, B, C, 0, 0, 0)

#if __has_builtin(__builtin_amdgcn_exp2f)
#define EXP2(x) __builtin_amdgcn_exp2f(x)
#else
#define EXP2(x) exp2f(x)
#endif

// gfx9 waitcnt imm: vmcnt[3:0] | expcnt<<4 | lgkmcnt<<8 | vmcnt[5:4]<<14 (exp/lgkm = no-wait)
#define WAIT_VM8() __builtin_amdgcn_s_waitcnt(0x0F78)  // keep 8 newest in flight
#define WAIT_VM0() __builtin_amdgcn_s_waitcnt(0x0F70)
#define SB0() __builtin_amdgcn_sched_barrier(0)

__device__ __forceinline__ unsigned short f2bf(float f) {  // RNE
  u32 u = __builtin_bit_cast(u32, f);
  u += 0x7FFFu + ((u >> 16) & 1u);
  return (unsigned short)(u >> 16);
}
// async 16B/lane global->LDS: lds dst = wave-uniform base + lane*16
__device__ __forceinline__ void load_lds16(const void* g, void* l) {
  __builtin_amdgcn_global_load_lds((const __attribute__((address_space(1))) u32*)g,
                                   (__attribute__((address_space(3))) u32*)l, 16, 0, 0);
}

// Prep (512 blocks): K slab fp32->bf16 (plain [b][key][d]) + V 64-key tile ->
// vt[b][w][d][32key] bf16 (32-key windows w=0..127, natural key order inside window).
__global__ __launch_bounds__(256) void prep_kv(
    const float* __restrict__ k, const float* __restrict__ v,
    unsigned short* __restrict__ kb, unsigned short* __restrict__ vt) {
  __shared__ float tileT[64 * 68];  // [d][key-in-64]
  const int blk = blockIdx.x, tid = threadIdx.x;
  size_t base = (size_t)blk * 4096 + tid * 4;
#pragma unroll
  for (int i = 0; i < 4; i++) {
    size_t off = base + (size_t)i * 1024;
    floatx4 f = *(const floatx4*)(k + off);
    ushortx4 h;
    h[0] = f2bf(f[0]); h[1] = f2bf(f[1]); h[2] = f2bf(f[2]); h[3] = f2bf(f[3]);
    *(ushortx4*)(kb + off) = h;
  }
  // V: block = (b, h) covering keys [h*64, h*64+64) -> windows 2h, 2h+1
  const int b = blk >> 6, h = blk & 63;
  const int r = tid >> 2, c4 = (tid & 3) * 16;
  const float* vp = v + ((size_t)b * 4096 + h * 64 + r) * 64 + c4;
#pragma unroll
  for (int i = 0; i < 4; i++) {
    floatx4 f = *(const floatx4*)(vp + i * 4);
#pragma unroll
    for (int j = 0; j < 4; j++) tileT[(c4 + i * 4 + j) * 68 + r] = f[j];
  }
  __syncthreads();
  const int d = tid >> 2, g = tid & 3;
  unsigned short* vb = vt + (size_t)b * 262144 + ((h >> 1) * 4 + (h & 1) * 2) * 2048;
#pragma unroll
  for (int s = 0; s < 2; s++) {
    const float* src = tileT + d * 68 + s * 32 + g * 8;
    floatx4 f0 = *(const floatx4*)src;
    floatx4 f1 = *(const floatx4*)(src + 4);
    ushortx8 hh;
#pragma unroll
    for (int j = 0; j < 4; j++) { hh[j] = f2bf(f0[j]); hh[4 + j] = f2bf(f1[j]); }
    *(ushortx8*)(vb + s * 2048 + d * 32 + g * 8) = hh;
  }
}

// Attention: 1024 blocks x 256 thr (4 waves), 32-row Q-tiles -> 4 blocks/CU
// (16 waves/CU = 4/SIMD), barrier-free loop. Halved Q-tile halves accumulator
// registers (o: 32 regs, qf: 16) so the (256,4) 128-VGPR cap fits WITHOUT spill
// (round-1 lesson: (512,4) at 64 VGPR spilled 894 MB/dispatch to scratch).
// Each wave owns a private 32-key window per 128-key tile; K staged via DMA 1 tile
// ahead into 2 wave-private LDS bufs (row-PERMUTED so two 16-key QK tiles concatenate
// into one K32 PV B-frag); V register ping-pong 1 tile ahead; per-iter wait =
// s_waitcnt vmcnt(8) (K(t+1)+V(t+1) stay in flight). Softmax denom l on VALU
// (8 adds/phase/nt + end-of-loop shfl_xor) instead of ones-MFMA: saves 20 regs.
// S^T=K*Q^T -> C-layout==PV B-frag layout -> P register-direct.
__global__ __launch_bounds__(256, 4) void attn(
    const float* __restrict__ q, const unsigned short* __restrict__ kb,
    const unsigned short* __restrict__ vt, const float* __restrict__ mask,
    float* __restrict__ out) {
  // loop: 4 waves x 2 K bufs x 2048 ushorts = 32768 B (wave-private)
  // epilogue reuses: obuf 2x[32][72] fp32 + lbuf [4][32] = 18944 B
  __shared__ __align__(16) char smem_raw[32768];
  unsigned short* smem = (unsigned short*)smem_raw;
  const int tid = threadIdx.x;
  const int wave = tid >> 6, lane = tid & 63;
  const int c = lane & 15, quad = lane >> 4;
  const int b = blockIdx.x & 7, qt = blockIdx.x >> 3;  // blk%8=batch -> per-XCD L2 locality
  const int q0 = qt * 32;

  const unsigned short* kB = kb + (size_t)b * (4096 * 64);
  const unsigned short* vtB = vt + (size_t)b * 262144;

  // Q B-frags (B[k=d=kc*32+quad*8+j][n=q=c]), loop-invariant; fold (1/8)*log2(e)
  const float qscale = 0.18033688011112042f;
  short8 qf[2][2];
#pragma unroll
  for (int nt = 0; nt < 2; nt++)
#pragma unroll
    for (int kc = 0; kc < 2; kc++) {
      const float* qp = q + ((size_t)b * 4096 + q0 + nt * 16 + c) * 64 + kc * 32 + quad * 8;
      floatx4 f0 = *(const floatx4*)qp;
      floatx4 f1 = *(const floatx4*)(qp + 4);
      short8 s;
#pragma unroll
      for (int j = 0; j < 4; j++) {
        s[j] = (short)f2bf(f0[j] * qscale);
        s[4 + j] = (short)f2bf(f1[j] * qscale);
      }
      qf[nt][kc] = s;
    }

  floatx4 o[4][2];   // O^T[d=mt*16+quad*4+r][q=nt*16+c]
  float l_acc[2];    // per-lane partial softmax denom (keys quad*8+j over windows)
#pragma unroll
  for (int mt = 0; mt < 4; mt++)
#pragma unroll
    for (int nt = 0; nt < 2; nt++) o[mt][nt] = (floatx4){0.f, 0.f, 0.f, 0.f};
  l_acc[0] = 0.f; l_acc[1] = 0.f;

  const int r8 = lane >> 3, cs8 = lane & 7;
  const int klane = (r8 >> 2) * 8 + (r8 & 3);  // row-permutation: C row (quad,r) -> key quad*8+r
  unsigned short* wbase = smem + wave * 4096;  // 2 bufs x 2048
  const unsigned short* gK0 = kB + (size_t)(wave * 32 + klane) * 64 + (cs8 ^ r8) * 8;
  const unsigned short* gV0 = vtB + wave * 2048 + c * 32 + quad * 8;

  auto stageK = [&](int t, int buf) {  // 4KB: tileA (keys {q8+0..3}) | tileB ({q8+4..7})
    unsigned short* Kd = wbase + buf * 2048;
    const unsigned short* gk = gK0 + (size_t)t * 8192;  // tile = 128 keys (4 waves x 32)
    load_lds16(gk, Kd);                   // tileA rows 0-7   (key off  0)
    load_lds16(gk + 16 * 64, Kd + 512);   // tileA rows 8-15  (key off 16)
    load_lds16(gk + 4 * 64, Kd + 1024);   // tileB rows 0-7   (key off  4)
    load_lds16(gk + 20 * 64, Kd + 1536);  // tileB rows 8-15  (key off 20)
  };
  auto loadV = [&](u32x4* vv, int t) {  // 4 x 1KB-coalesced register loads
    const unsigned short* gv = gV0 + (size_t)t * 8192;
#pragma unroll
    for (int mt = 0; mt < 4; mt++) vv[mt] = *(const u32x4*)(gv + mt * 512);
  };

  auto compute = [&](const unsigned short* Kbuf, const u32x4* vv) {
    short8 kfA[2], kfB[2];  // A[m=key][k=d]; phys slot = (kc*4+quad)^(c&7)
#pragma unroll
    for (int kc = 0; kc < 2; kc++) {
      const int sl = ((kc * 4 + quad) ^ (c & 7)) * 8;
      kfA[kc] = *(const short8*)(Kbuf + c * 64 + sl);
      kfB[kc] = *(const short8*)(Kbuf + 1024 + c * 64 + sl);
    }
#pragma unroll
    for (int nt = 0; nt < 2; nt++) {
      floatx4 sA = (floatx4){0.f, 0.f, 0.f, 0.f}, sB = sA;
      sA = MFMA_K32(kfA[0], qf[nt][0], sA);
      sA = MFMA_K32(kfA[1], qf[nt][1], sA);
      sB = MFMA_K32(kfB[0], qf[nt][0], sB);
      sB = MFMA_K32(kfB[1], qf[nt][1], sB);
      // P^T[key=quad*8+j][q=nt*16+c]: A gives j=0..3, B gives j=4..7 (row-permuted staging)
      float eA0 = EXP2(sA[0]), eA1 = EXP2(sA[1]), eA2 = EXP2(sA[2]), eA3 = EXP2(sA[3]);
      float eB0 = EXP2(sB[0]), eB1 = EXP2(sB[1]), eB2 = EXP2(sB[2]), eB3 = EXP2(sB[3]);
      l_acc[nt] += ((eA0 + eA1) + (eA2 + eA3)) + ((eB0 + eB1) + (eB2 + eB3));
      u32 a0 = __builtin_bit_cast(u32, eA0), a1 = __builtin_bit_cast(u32, eA1);
      u32 a2 = __builtin_bit_cast(u32, eA2), a3 = __builtin_bit_cast(u32, eA3);
      u32 b0 = __builtin_bit_cast(u32, eB0), b1 = __builtin_bit_cast(u32, eB1);
      u32 b2 = __builtin_bit_cast(u32, eB2), b3 = __builtin_bit_cast(u32, eB3);
      u32x4 pw = {__builtin_amdgcn_perm(a1, a0, 0x07060302u),
                  __builtin_amdgcn_perm(a3, a2, 0x07060302u),
                  __builtin_amdgcn_perm(b1, b0, 0x07060302u),
                  __builtin_amdgcn_perm(b3, b2, 0x07060302u)};
      short8 pf = __builtin_bit_cast(short8, pw);  // K32 B-frag: B[k=quad*8+j][n=c]
#pragma unroll
      for (int mt = 0; mt < 4; mt++)
        o[mt][nt] = MFMA_K32(__builtin_bit_cast(short8, vv[mt]), pf, o[mt][nt]);
    }
  };

  u32x4 vvA[4], vvB[4];
  stageK(0, 0);
  loadV(vvA, 0);
  stageK(1, 1);

  // Steady state in flight at each WAIT: K(t),V(t),K(t+1),V(t+1) = 16; vmcnt(8)
  // completes the 8 oldest (= K(t),V(t)). stageK(t+2) reuses the buffer compute(t)
  // just read: safe by program order (ds_reads consumed via lgkmcnt before the
  // MFMAs that precede the DMA issue) + SB0 pinning the DMA after the compute.
#pragma unroll 1
  for (int tt = 0; tt < 15; tt++) {
    const int t0 = 2 * tt;
    loadV(vvB, t0 + 1);
    WAIT_VM8();
    SB0();
    compute(wbase, vvA);  // buf0 (t even)
    SB0();
    stageK(t0 + 2, 0);
    loadV(vvA, t0 + 2);
    WAIT_VM8();
    SB0();
    compute(wbase + 2048, vvB);  // buf1 (t odd)
    SB0();
    stageK(t0 + 3, 1);
  }
  // tail: t = 30, 31 (K30,K31,V30 issued in last loop iter)
  loadV(vvB, 31);
  WAIT_VM8();
  SB0();
  compute(wbase, vvA);
  WAIT_VM0();
  SB0();
  compute(wbase + 2048, vvB);

  // per-wave l: sum across quads (lanes c, c+16, c+32, c+48)
  float lw[2];
#pragma unroll
  for (int nt = 0; nt < 2; nt++) {
    float l = l_acc[nt];
    l += __shfl_xor(l, 16);
    l += __shfl_xor(l, 32);
    lw[nt] = l;
  }

  // ---- merge 4 wave-partials (first barriers since loop start) ----
  __syncthreads();
  float* obuf = (float*)smem_raw;  // 2 x [32 q][72]
  float* lbuf = obuf + 4608;       // [4 waves][32 q]
  if (lane < 16) {
#pragma unroll
    for (int nt = 0; nt < 2; nt++) lbuf[wave * 32 + nt * 16 + c] = lw[nt];
  }
  if (wave < 2) {
    float* ob = obuf + wave * 2304;
#pragma unroll
    for (int mt = 0; mt < 4; mt++)
#pragma unroll
      for (int nt = 0; nt < 2; nt++)
        *(floatx4*)(ob + (nt * 16 + c) * 72 + mt * 16 + quad * 4) = o[mt][nt];
  }
  __syncthreads();
  if (wave >= 2) {
    float* ob = obuf + (wave - 2) * 2304;
#pragma unroll
    for (int mt = 0; mt < 4; mt++)
#pragma unroll
      for (int nt = 0; nt < 2; nt++) {
        float* a = ob + (nt * 16 + c) * 72 + mt * 16 + quad * 4;
        floatx4 cur = *(floatx4*)a;
        *(floatx4*)a = cur + o[mt][nt];
      }
  }
  __syncthreads();

  // out = O/l * mask, coalesced stores (256 threads: 8 cols x 32 rows each)
  const int row = tid >> 3, dg = (tid & 7) * 8;
  const float l = lbuf[row] + lbuf[32 + row] + lbuf[64 + row] + lbuf[96 + row];
  const float sc = mask[b * 4096 + q0 + row] / l;
  float* op = out + ((size_t)b * 4096 + q0 + row) * 64 + dg;
#pragma unroll
  for (int i = 0; i < 2; i++) {
    floatx4 a = *(const floatx4*)(obuf + row * 72 + dg + i * 4);
    floatx4 b2 = *(const floatx4*)(obuf + 2304 + row * 72 + dg + i * 4);
    *(floatx4*)(op + i * 4) = (a + b2) * sc;
  }
}

extern "C" void kernel_launch(void* const* d_in, const int* in_sizes, int n_in,
                              void* d_out, int out_size, void* d_ws, size_t ws_size,
                              hipStream_t stream) {
  const float* q = (const float*)d_in[0];
  const float* k = (const float*)d_in[1];
  const float* v = (const float*)d_in[2];
  const float* mask = (const float*)d_in[3];
  unsigned short* kb = (unsigned short*)d_ws;  // 4 MB
  unsigned short* vt = kb + 8 * 4096 * 64;     // 4 MB (needs ws >= 8 MB)
  prep_kv<<<512, 256, 0, stream>>>(k, v, kb, vt);
  attn<<<1024, 256, 0, stream>>>(q, kb, vt, mask, (float*)d_out);
}

// Round 3
// 253.314 us; speedup vs baseline: 13915.4636x; 13915.4636x over previous
//
#include <hip/hip_runtime.h>

typedef __attribute__((ext_vector_type(8))) short short8;
typedef __attribute__((ext_vector_type(4))) float floatx4;
typedef __attribute__((ext_vector_type(4))) unsigned short ushortx4;
typedef __attribute__((ext_vector_type(8))) unsigned short ushortx8;
typedef unsigned int u32;
typedef __attribute__((ext_vector_type(2))) u32 u32x2;
typedef __attribute__((ext_vector_type(4))) u32 u32x4;

#define MFMA_K32(A, B, C) __builtin_amdgcn_mfma_f32_16x16x32_bf16(A, B, C, 0, 0, 0)

#if __has_builtin(__builtin_amdgcn_exp2f)
#define EXP2(x) __builtin_amdgcn_exp2f(x)
#else
#define EXP2(x) exp2f(x)
#endif

// gfx9 waitcnt imm: vmcnt[3:0] | expcnt<<4 | lgkmcnt<<8 | vmcnt[5:4]<<14 (exp/lgkm = no-wait)
#define WAIT_VM12() __builtin_amdgcn_s_waitcnt(0x0F7C)  // keep 12 newest in flight
#define WAIT_VM8() __builtin_amdgcn_s_waitcnt(0x0F78)
#define WAIT_VM0() __builtin_amdgcn_s_waitcnt(0x0F70)
#define SB0() __builtin_amdgcn_sched_barrier(0)

__device__ __forceinline__ unsigned short f2bf(float f) {  // RNE
  u32 u = __builtin_bit_cast(u32, f);
  u += 0x7FFFu + ((u >> 16) & 1u);
  return (unsigned short)(u >> 16);
}
// async 16B/lane global->LDS: lds dst = wave-uniform base + lane*16
__device__ __forceinline__ void load_lds16(const void* g, void* l) {
  __builtin_amdgcn_global_load_lds((const __attribute__((address_space(1))) u32*)g,
                                   (__attribute__((address_space(3))) u32*)l, 16, 0, 0);
}

// Prep (512 blocks): K slab fp32->bf16 (plain [b][key][d]) + V 64-key tile ->
// vt[b][w][d][32key] bf16 (32-key windows w=0..127, natural key order inside window).
__global__ __launch_bounds__(256) void prep_kv(
    const float* __restrict__ k, const float* __restrict__ v,
    unsigned short* __restrict__ kb, unsigned short* __restrict__ vt) {
  __shared__ float tileT[64 * 68];  // [d][key-in-64]
  const int blk = blockIdx.x, tid = threadIdx.x;
  size_t base = (size_t)blk * 4096 + tid * 4;
#pragma unroll
  for (int i = 0; i < 4; i++) {
    size_t off = base + (size_t)i * 1024;
    floatx4 f = *(const floatx4*)(k + off);
    ushortx4 h;
    h[0] = f2bf(f[0]); h[1] = f2bf(f[1]); h[2] = f2bf(f[2]); h[3] = f2bf(f[3]);
    *(ushortx4*)(kb + off) = h;
  }
  // V: block = (b, h) covering keys [h*64, h*64+64) -> windows 2h, 2h+1
  const int b = blk >> 6, h = blk & 63;
  const int r = tid >> 2, c4 = (tid & 3) * 16;
  const float* vp = v + ((size_t)b * 4096 + h * 64 + r) * 64 + c4;
#pragma unroll
  for (int i = 0; i < 4; i++) {
    floatx4 f = *(const floatx4*)(vp + i * 4);
#pragma unroll
    for (int j = 0; j < 4; j++) tileT[(c4 + i * 4 + j) * 68 + r] = f[j];
  }
  __syncthreads();
  const int d = tid >> 2, g = tid & 3;
  unsigned short* vb = vt + (size_t)b * 262144 + ((h >> 1) * 4 + (h & 1) * 2) * 2048;
#pragma unroll
  for (int s = 0; s < 2; s++) {
    const float* src = tileT + d * 68 + s * 32 + g * 8;
    floatx4 f0 = *(const floatx4*)src;
    floatx4 f1 = *(const floatx4*)(src + 4);
    ushortx8 hh;
#pragma unroll
    for (int j = 0; j < 4; j++) { hh[j] = f2bf(f0[j]); hh[4 + j] = f2bf(f1[j]); }
    *(ushortx8*)(vb + s * 2048 + d * 32 + g * 8) = hh;
  }
}

// Attention: 1024 blocks x 256 thr (4 waves), 32-row Q-tiles, barrier-free loop.
// Occupancy target: 3 blocks/CU (12 waves/CU = 3/SIMD) -- LDS 48 KB/block (3 bufs)
// and (256,3) reg cap ~170 vs ~130 demand (40 regs slack -> no spill BY CONSTRUCTION;
// rounds 1-2 showed caps below demand spill into the loop and poison the hand-counted
// vmcnt schedule). Pipeline = verified round-0 depth: K staged via DMA 2 tiles ahead
// into 3 wave-private LDS bufs (row-PERMUTED so two 16-key QK tiles concatenate into
// one K32 PV B-frag); V register ping-pong 1 tile ahead; steady-state wait =
// s_waitcnt vmcnt(12) (K(t+1),V(t+1),K(t+2) stay in flight). Loop unrolled 6 tiles/iter
// so buf(t)=t%3 and vv parity are position-constants. Softmax denom l on VALU.
// S^T=K*Q^T -> C-layout==PV B-frag layout -> P register-direct.
__global__ __launch_bounds__(256, 3) void attn(
    const float* __restrict__ q, const unsigned short* __restrict__ kb,
    const unsigned short* __restrict__ vt, const float* __restrict__ mask,
    float* __restrict__ out) {
  // loop: 4 waves x 3 K bufs x 2048 ushorts = 49152 B (wave-private)
  // epilogue reuses: obuf 2x[32][72] fp32 + lbuf [4][32] = 18944 B
  __shared__ __align__(16) char smem_raw[49152];
  unsigned short* smem = (unsigned short*)smem_raw;
  const int tid = threadIdx.x;
  const int wave = tid >> 6, lane = tid & 63;
  const int c = lane & 15, quad = lane >> 4;
  const int b = blockIdx.x & 7, qt = blockIdx.x >> 3;  // blk%8=batch -> per-XCD L2 locality
  const int q0 = qt * 32;

  const unsigned short* kB = kb + (size_t)b * (4096 * 64);
  const unsigned short* vtB = vt + (size_t)b * 262144;

  // Q B-frags (B[k=d=kc*32+quad*8+j][n=q=c]), loop-invariant; fold (1/8)*log2(e)
  const float qscale = 0.18033688011112042f;
  short8 qf[2][2];
#pragma unroll
  for (int nt = 0; nt < 2; nt++)
#pragma unroll
    for (int kc = 0; kc < 2; kc++) {
      const float* qp = q + ((size_t)b * 4096 + q0 + nt * 16 + c) * 64 + kc * 32 + quad * 8;
      floatx4 f0 = *(const floatx4*)qp;
      floatx4 f1 = *(const floatx4*)(qp + 4);
      short8 s;
#pragma unroll
      for (int j = 0; j < 4; j++) {
        s[j] = (short)f2bf(f0[j] * qscale);
        s[4 + j] = (short)f2bf(f1[j] * qscale);
      }
      qf[nt][kc] = s;
    }

  floatx4 o[4][2];   // O^T[d=mt*16+quad*4+r][q=nt*16+c]
  float l_acc[2];    // per-lane partial softmax denom (keys quad*8+j over windows)
#pragma unroll
  for (int mt = 0; mt < 4; mt++)
#pragma unroll
    for (int nt = 0; nt < 2; nt++) o[mt][nt] = (floatx4){0.f, 0.f, 0.f, 0.f};
  l_acc[0] = 0.f; l_acc[1] = 0.f;

  const int r8 = lane >> 3, cs8 = lane & 7;
  const int klane = (r8 >> 2) * 8 + (r8 & 3);  // row-permutation: C row (quad,r) -> key quad*8+r
  unsigned short* wbase = smem + wave * 6144;  // 3 bufs x 2048
  const unsigned short* gK0 = kB + (size_t)(wave * 32 + klane) * 64 + (cs8 ^ r8) * 8;
  const unsigned short* gV0 = vtB + wave * 2048 + c * 32 + quad * 8;

  auto stageK = [&](int t, int buf) {  // 4KB: tileA (keys {q8+0..3}) | tileB ({q8+4..7})
    unsigned short* Kd = wbase + buf * 2048;
    const unsigned short* gk = gK0 + (size_t)t * 8192;  // tile = 128 keys (4 waves x 32)
    load_lds16(gk, Kd);                   // tileA rows 0-7   (key off  0)
    load_lds16(gk + 16 * 64, Kd + 512);   // tileA rows 8-15  (key off 16)
    load_lds16(gk + 4 * 64, Kd + 1024);   // tileB rows 0-7   (key off  4)
    load_lds16(gk + 20 * 64, Kd + 1536);  // tileB rows 8-15  (key off 20)
  };
  auto loadV = [&](u32x4* vv, int t) {  // 4 x 1KB-coalesced register loads
    const unsigned short* gv = gV0 + (size_t)t * 8192;
#pragma unroll
    for (int mt = 0; mt < 4; mt++) vv[mt] = *(const u32x4*)(gv + mt * 512);
  };

  auto compute = [&](const unsigned short* Kbuf, const u32x4* vv) {
    short8 kfA[2], kfB[2];  // A[m=key][k=d]; phys slot = (kc*4+quad)^(c&7)
#pragma unroll
    for (int kc = 0; kc < 2; kc++) {
      const int sl = ((kc * 4 + quad) ^ (c & 7)) * 8;
      kfA[kc] = *(const short8*)(Kbuf + c * 64 + sl);
      kfB[kc] = *(const short8*)(Kbuf + 1024 + c * 64 + sl);
    }
#pragma unroll
    for (int nt = 0; nt < 2; nt++) {
      floatx4 sA = (floatx4){0.f, 0.f, 0.f, 0.f}, sB = sA;
      sA = MFMA_K32(kfA[0], qf[nt][0], sA);
      sA = MFMA_K32(kfA[1], qf[nt][1], sA);
      sB = MFMA_K32(kfB[0], qf[nt][0], sB);
      sB = MFMA_K32(kfB[1], qf[nt][1], sB);
      // P^T[key=quad*8+j][q=nt*16+c]: A gives j=0..3, B gives j=4..7 (row-permuted staging)
      float eA0 = EXP2(sA[0]), eA1 = EXP2(sA[1]), eA2 = EXP2(sA[2]), eA3 = EXP2(sA[3]);
      float eB0 = EXP2(sB[0]), eB1 = EXP2(sB[1]), eB2 = EXP2(sB[2]), eB3 = EXP2(sB[3]);
      l_acc[nt] += ((eA0 + eA1) + (eA2 + eA3)) + ((eB0 + eB1) + (eB2 + eB3));
      u32 a0 = __builtin_bit_cast(u32, eA0), a1 = __builtin_bit_cast(u32, eA1);
      u32 a2 = __builtin_bit_cast(u32, eA2), a3 = __builtin_bit_cast(u32, eA3);
      u32 b0 = __builtin_bit_cast(u32, eB0), b1 = __builtin_bit_cast(u32, eB1);
      u32 b2 = __builtin_bit_cast(u32, eB2), b3 = __builtin_bit_cast(u32, eB3);
      u32x4 pw = {__builtin_amdgcn_perm(a1, a0, 0x07060302u),
                  __builtin_amdgcn_perm(a3, a2, 0x07060302u),
                  __builtin_amdgcn_perm(b1, b0, 0x07060302u),
                  __builtin_amdgcn_perm(b3, b2, 0x07060302u)};
      short8 pf = __builtin_bit_cast(short8, pw);  // K32 B-frag: B[k=quad*8+j][n=c]
#pragma unroll
      for (int mt = 0; mt < 4; mt++)
        o[mt][nt] = MFMA_K32(__builtin_bit_cast(short8, vv[mt]), pf, o[mt][nt]);
    }
  };

  u32x4 vvA[4], vvB[4];
  stageK(0, 0);
  loadV(vvA, 0);
  stageK(1, 1);
  // Outstanding: K0,V0,K1 = 12.
  // Per tile t: loadV(t+1), stageK(t+2) -> 20 outstanding; WAIT_VM12 completes the
  // 8 oldest = K(t),V(t); compute(t). stageK(t+2) reuses the buffer compute(t-1)
  // already consumed (ds_reads drained by lgkmcnt before its MFMAs). 6 tiles/iter
  // so buf=t%3 and vvA/vvB parity are position-constant.
#pragma unroll 1
  for (int it = 0; it < 5; it++) {
    const int t0 = 6 * it;
    loadV(vvB, t0 + 1); stageK(t0 + 2, 2);
    WAIT_VM12(); SB0();
    compute(wbase, vvA); SB0();

    loadV(vvA, t0 + 2); stageK(t0 + 3, 0);
    WAIT_VM12(); SB0();
    compute(wbase + 2048, vvB); SB0();

    loadV(vvB, t0 + 3); stageK(t0 + 4, 1);
    WAIT_VM12(); SB0();
    compute(wbase + 4096, vvA); SB0();

    loadV(vvA, t0 + 4); stageK(t0 + 5, 2);
    WAIT_VM12(); SB0();
    compute(wbase, vvB); SB0();

    loadV(vvB, t0 + 5); stageK(t0 + 6, 0);
    WAIT_VM12(); SB0();
    compute(wbase + 2048, vvA); SB0();

    loadV(vvA, t0 + 6); stageK(t0 + 7, 1);
    WAIT_VM12(); SB0();
    compute(wbase + 4096, vvB); SB0();
  }
  // After loop: outstanding = K30,V30,K31 = 12.
  // t=30 (buf0, vvA): load V31 -> 16; vmcnt(8) completes K30,V30.
  loadV(vvB, 31);
  WAIT_VM8(); SB0();
  compute(wbase, vvA); SB0();
  // t=31 (buf1, vvB)
  WAIT_VM0(); SB0();
  compute(wbase + 2048, vvB);

  // per-wave l: sum across quads (lanes c, c+16, c+32, c+48)
  float lw[2];
#pragma unroll
  for (int nt = 0; nt < 2; nt++) {
    float l = l_acc[nt];
    l += __shfl_xor(l, 16);
    l += __shfl_xor(l, 32);
    lw[nt] = l;
  }

  // ---- merge 4 wave-partials (first barriers since loop start) ----
  __syncthreads();
  float* obuf = (float*)smem_raw;  // 2 x [32 q][72]
  float* lbuf = obuf + 4608;       // [4 waves][32 q]
  if (lane < 16) {
#pragma unroll
    for (int nt = 0; nt < 2; nt++) lbuf[wave * 32 + nt * 16 + c] = lw[nt];
  }
  if (wave < 2) {
    float* ob = obuf + wave * 2304;
#pragma unroll
    for (int mt = 0; mt < 4; mt++)
#pragma unroll
      for (int nt = 0; nt < 2; nt++)
        *(floatx4*)(ob + (nt * 16 + c) * 72 + mt * 16 + quad * 4) = o[mt][nt];
  }
  __syncthreads();
  if (wave >= 2) {
    float* ob = obuf + (wave - 2) * 2304;
#pragma unroll
    for (int mt = 0; mt < 4; mt++)
#pragma unroll
      for (int nt = 0; nt < 2; nt++) {
        float* a = ob + (nt * 16 + c) * 72 + mt * 16 + quad * 4;
        floatx4 cur = *(floatx4*)a;
        *(floatx4*)a = cur + o[mt][nt];
      }
  }
  __syncthreads();

  // out = O/l * mask, coalesced stores (256 threads: 8 cols x 32 rows each)
  const int row = tid >> 3, dg = (tid & 7) * 8;
  const float l = lbuf[row] + lbuf[32 + row] + lbuf[64 + row] + lbuf[96 + row];
  const float sc = mask[b * 4096 + q0 + row] / l;
  float* op = out + ((size_t)b * 4096 + q0 + row) * 64 + dg;
#pragma unroll
  for (int i = 0; i < 2; i++) {
    floatx4 a = *(const floatx4*)(obuf + row * 72 + dg + i * 4);
    floatx4 b2 = *(const floatx4*)(obuf + 2304 + row * 72 + dg + i * 4);
    *(floatx4*)(op + i * 4) = (a + b2) * sc;
  }
}

extern "C" void kernel_launch(void* const* d_in, const int* in_sizes, int n_in,
                              void* d_out, int out_size, void* d_ws, size_t ws_size,
                              hipStream_t stream) {
  const float* q = (const float*)d_in[0];
  const float* k = (const float*)d_in[1];
  const float* v = (const float*)d_in[2];
  const float* mask = (const float*)d_in[3];
  unsigned short* kb = (unsigned short*)d_ws;  // 4 MB
  unsigned short* vt = kb + 8 * 4096 * 64;     // 4 MB (needs ws >= 8 MB)
  prep_kv<<<512, 256, 0, stream>>>(k, v, kb, vt);
  attn<<<1024, 256, 0, stream>>>(q, kb, vt, mask, (float*)d_out);
}

// Round 4
// 138.926 us; speedup vs baseline: 25373.1928x; 1.8234x over previous
//
#include <hip/hip_runtime.h>

typedef __attribute__((ext_vector_type(8))) short short8;
typedef __attribute__((ext_vector_type(4))) float floatx4;
typedef __attribute__((ext_vector_type(4))) unsigned short ushortx4;
typedef __attribute__((ext_vector_type(8))) unsigned short ushortx8;
typedef unsigned int u32;
typedef __attribute__((ext_vector_type(2))) u32 u32x2;
typedef __attribute__((ext_vector_type(4))) u32 u32x4;

#define MFMA_K32(A, B, C) __builtin_amdgcn_mfma_f32_16x16x32_bf16(A, B, C, 0, 0, 0)

#if __has_builtin(__builtin_amdgcn_exp2f)
#define EXP2(x) __builtin_amdgcn_exp2f(x)
#else
#define EXP2(x) exp2f(x)
#endif

// gfx9 waitcnt imm: vmcnt[3:0] | expcnt<<4 | lgkmcnt<<8 | vmcnt[5:4]<<14 (exp/lgkm = no-wait)
#define WAIT_VM12() __builtin_amdgcn_s_waitcnt(0x0F7C)  // keep 12 newest in flight
#define WAIT_VM8() __builtin_amdgcn_s_waitcnt(0x0F78)
#define WAIT_VM0() __builtin_amdgcn_s_waitcnt(0x0F70)
#define SB0() __builtin_amdgcn_sched_barrier(0)

__device__ __forceinline__ unsigned short f2bf(float f) {  // RNE
  u32 u = __builtin_bit_cast(u32, f);
  u += 0x7FFFu + ((u >> 16) & 1u);
  return (unsigned short)(u >> 16);
}
// async 16B/lane global->LDS: lds dst = wave-uniform base + lane*16
__device__ __forceinline__ void load_lds16(const void* g, void* l) {
  __builtin_amdgcn_global_load_lds((const __attribute__((address_space(1))) u32*)g,
                                   (__attribute__((address_space(3))) u32*)l, 16, 0, 0);
}

// Prep (512 blocks): K slab fp32->bf16 (plain [b][key][d]) + V 64-key tile ->
// vt[b][w][d][32key] bf16 (32-key windows w=0..127, natural key order inside window).
__global__ __launch_bounds__(256) void prep_kv(
    const float* __restrict__ k, const float* __restrict__ v,
    unsigned short* __restrict__ kb, unsigned short* __restrict__ vt) {
  __shared__ float tileT[64 * 68];  // [d][key-in-64]
  const int blk = blockIdx.x, tid = threadIdx.x;
  size_t base = (size_t)blk * 4096 + tid * 4;
#pragma unroll
  for (int i = 0; i < 4; i++) {
    size_t off = base + (size_t)i * 1024;
    floatx4 f = *(const floatx4*)(k + off);
    ushortx4 h;
    h[0] = f2bf(f[0]); h[1] = f2bf(f[1]); h[2] = f2bf(f[2]); h[3] = f2bf(f[3]);
    *(ushortx4*)(kb + off) = h;
  }
  // V: block = (b, h) covering keys [h*64, h*64+64) -> windows 2h, 2h+1
  const int b = blk >> 6, h = blk & 63;
  const int r = tid >> 2, c4 = (tid & 3) * 16;
  const float* vp = v + ((size_t)b * 4096 + h * 64 + r) * 64 + c4;
#pragma unroll
  for (int i = 0; i < 4; i++) {
    floatx4 f = *(const floatx4*)(vp + i * 4);
#pragma unroll
    for (int j = 0; j < 4; j++) tileT[(c4 + i * 4 + j) * 68 + r] = f[j];
  }
  __syncthreads();
  const int d = tid >> 2, g = tid & 3;
  unsigned short* vb = vt + (size_t)b * 262144 + ((h >> 1) * 4 + (h & 1) * 2) * 2048;
#pragma unroll
  for (int s = 0; s < 2; s++) {
    const float* src = tileT + d * 68 + s * 32 + g * 8;
    floatx4 f0 = *(const floatx4*)src;
    floatx4 f1 = *(const floatx4*)(src + 4);
    ushortx8 hh;
#pragma unroll
    for (int j = 0; j < 4; j++) { hh[j] = f2bf(f0[j]); hh[4 + j] = f2bf(f1[j]); }
    *(ushortx8*)(vb + s * 2048 + d * 32 + g * 8) = hh;
  }
}

// Attention: 1024 blocks x 256 thr (4 waves), 32-row Q-tiles, barrier-free loop.
// NO min-waves launch-bounds hint: rounds 1-3 proved any min_waves>=3 hint makes the
// allocator split the unified gfx950 VGPR/AGPR file and cap arch-VGPRs below demand
// (64/84 reported), spilling 0.5-0.9 GB/dispatch into the hand-counted vmcnt loop.
// Natural allocation (~140 total) -> 3 waves/SIMD, matching LDS (48 KB -> 3 blocks/CU).
// Pipeline = verified round-0 depth: K staged via DMA 2 tiles ahead into 3
// wave-private LDS bufs (row-PERMUTED so two 16-key QK tiles concatenate into one
// K32 PV B-frag); V register ping-pong 1 tile ahead; steady-state wait =
// s_waitcnt vmcnt(12) (K(t+1),V(t+1),K(t+2) stay in flight). Loop unrolled 6 tiles/iter
// so buf(t)=t%3 and vv parity are position-constants. Softmax denom l on VALU.
// S^T=K*Q^T -> C-layout==PV B-frag layout -> P register-direct.
__global__ __launch_bounds__(256) void attn(
    const float* __restrict__ q, const unsigned short* __restrict__ kb,
    const unsigned short* __restrict__ vt, const float* __restrict__ mask,
    float* __restrict__ out) {
  // loop: 4 waves x 3 K bufs x 2048 ushorts = 49152 B (wave-private)
  // epilogue reuses: obuf 2x[32][72] fp32 + lbuf [4][32] = 18944 B
  __shared__ __align__(16) char smem_raw[49152];
  unsigned short* smem = (unsigned short*)smem_raw;
  const int tid = threadIdx.x;
  const int wave = tid >> 6, lane = tid & 63;
  const int c = lane & 15, quad = lane >> 4;
  const int b = blockIdx.x & 7, qt = blockIdx.x >> 3;  // blk%8=batch -> per-XCD L2 locality
  const int q0 = qt * 32;

  const unsigned short* kB = kb + (size_t)b * (4096 * 64);
  const unsigned short* vtB = vt + (size_t)b * 262144;

  // Q B-frags (B[k=d=kc*32+quad*8+j][n=q=c]), loop-invariant; fold (1/8)*log2(e)
  const float qscale = 0.18033688011112042f;
  short8 qf[2][2];
#pragma unroll
  for (int nt = 0; nt < 2; nt++)
#pragma unroll
    for (int kc = 0; kc < 2; kc++) {
      const float* qp = q + ((size_t)b * 4096 + q0 + nt * 16 + c) * 64 + kc * 32 + quad * 8;
      floatx4 f0 = *(const floatx4*)qp;
      floatx4 f1 = *(const floatx4*)(qp + 4);
      short8 s;
#pragma unroll
      for (int j = 0; j < 4; j++) {
        s[j] = (short)f2bf(f0[j] * qscale);
        s[4 + j] = (short)f2bf(f1[j] * qscale);
      }
      qf[nt][kc] = s;
    }

  floatx4 o[4][2];   // O^T[d=mt*16+quad*4+r][q=nt*16+c]
  float l_acc[2];    // per-lane partial softmax denom (keys quad*8+j over windows)
#pragma unroll
  for (int mt = 0; mt < 4; mt++)
#pragma unroll
    for (int nt = 0; nt < 2; nt++) o[mt][nt] = (floatx4){0.f, 0.f, 0.f, 0.f};
  l_acc[0] = 0.f; l_acc[1] = 0.f;

  const int r8 = lane >> 3, cs8 = lane & 7;
  const int klane = (r8 >> 2) * 8 + (r8 & 3);  // row-permutation: C row (quad,r) -> key quad*8+r
  unsigned short* wbase = smem + wave * 6144;  // 3 bufs x 2048
  const unsigned short* gK0 = kB + (size_t)(wave * 32 + klane) * 64 + (cs8 ^ r8) * 8;
  const unsigned short* gV0 = vtB + wave * 2048 + c * 32 + quad * 8;

  auto stageK = [&](int t, int buf) {  // 4KB: tileA (keys {q8+0..3}) | tileB ({q8+4..7})
    unsigned short* Kd = wbase + buf * 2048;
    const unsigned short* gk = gK0 + (size_t)t * 8192;  // tile = 128 keys (4 waves x 32)
    load_lds16(gk, Kd);                   // tileA rows 0-7   (key off  0)
    load_lds16(gk + 16 * 64, Kd + 512);   // tileA rows 8-15  (key off 16)
    load_lds16(gk + 4 * 64, Kd + 1024);   // tileB rows 0-7   (key off  4)
    load_lds16(gk + 20 * 64, Kd + 1536);  // tileB rows 8-15  (key off 20)
  };
  auto loadV = [&](u32x4* vv, int t) {  // 4 x 1KB-coalesced register loads
    const unsigned short* gv = gV0 + (size_t)t * 8192;
#pragma unroll
    for (int mt = 0; mt < 4; mt++) vv[mt] = *(const u32x4*)(gv + mt * 512);
  };

  auto compute = [&](const unsigned short* Kbuf, const u32x4* vv) {
    short8 kfA[2], kfB[2];  // A[m=key][k=d]; phys slot = (kc*4+quad)^(c&7)
#pragma unroll
    for (int kc = 0; kc < 2; kc++) {
      const int sl = ((kc * 4 + quad) ^ (c & 7)) * 8;
      kfA[kc] = *(const short8*)(Kbuf + c * 64 + sl);
      kfB[kc] = *(const short8*)(Kbuf + 1024 + c * 64 + sl);
    }
#pragma unroll
    for (int nt = 0; nt < 2; nt++) {
      floatx4 sA = (floatx4){0.f, 0.f, 0.f, 0.f}, sB = sA;
      sA = MFMA_K32(kfA[0], qf[nt][0], sA);
      sA = MFMA_K32(kfA[1], qf[nt][1], sA);
      sB = MFMA_K32(kfB[0], qf[nt][0], sB);
      sB = MFMA_K32(kfB[1], qf[nt][1], sB);
      // P^T[key=quad*8+j][q=nt*16+c]: A gives j=0..3, B gives j=4..7 (row-permuted staging)
      float eA0 = EXP2(sA[0]), eA1 = EXP2(sA[1]), eA2 = EXP2(sA[2]), eA3 = EXP2(sA[3]);
      float eB0 = EXP2(sB[0]), eB1 = EXP2(sB[1]), eB2 = EXP2(sB[2]), eB3 = EXP2(sB[3]);
      l_acc[nt] += ((eA0 + eA1) + (eA2 + eA3)) + ((eB0 + eB1) + (eB2 + eB3));
      u32 a0 = __builtin_bit_cast(u32, eA0), a1 = __builtin_bit_cast(u32, eA1);
      u32 a2 = __builtin_bit_cast(u32, eA2), a3 = __builtin_bit_cast(u32, eA3);
      u32 b0 = __builtin_bit_cast(u32, eB0), b1 = __builtin_bit_cast(u32, eB1);
      u32 b2 = __builtin_bit_cast(u32, eB2), b3 = __builtin_bit_cast(u32, eB3);
      u32x4 pw = {__builtin_amdgcn_perm(a1, a0, 0x07060302u),
                  __builtin_amdgcn_perm(a3, a2, 0x07060302u),
                  __builtin_amdgcn_perm(b1, b0, 0x07060302u),
                  __builtin_amdgcn_perm(b3, b2, 0x07060302u)};
      short8 pf = __builtin_bit_cast(short8, pw);  // K32 B-frag: B[k=quad*8+j][n=c]
#pragma unroll
      for (int mt = 0; mt < 4; mt++)
        o[mt][nt] = MFMA_K32(__builtin_bit_cast(short8, vv[mt]), pf, o[mt][nt]);
    }
  };

  u32x4 vvA[4], vvB[4];
  stageK(0, 0);
  loadV(vvA, 0);
  stageK(1, 1);
  // Outstanding: K0,V0,K1 = 12.
  // Per tile t: loadV(t+1), stageK(t+2) -> 20 outstanding; WAIT_VM12 completes the
  // 8 oldest = K(t),V(t); compute(t). stageK(t+2) reuses the buffer compute(t-1)
  // already consumed (ds_reads drained by lgkmcnt before its MFMAs). 6 tiles/iter
  // so buf=t%3 and vvA/vvB parity are position-constant.
#pragma unroll 1
  for (int it = 0; it < 5; it++) {
    const int t0 = 6 * it;
    loadV(vvB, t0 + 1); stageK(t0 + 2, 2);
    WAIT_VM12(); SB0();
    compute(wbase, vvA); SB0();

    loadV(vvA, t0 + 2); stageK(t0 + 3, 0);
    WAIT_VM12(); SB0();
    compute(wbase + 2048, vvB); SB0();

    loadV(vvB, t0 + 3); stageK(t0 + 4, 1);
    WAIT_VM12(); SB0();
    compute(wbase + 4096, vvA); SB0();

    loadV(vvA, t0 + 4); stageK(t0 + 5, 2);
    WAIT_VM12(); SB0();
    compute(wbase, vvB); SB0();

    loadV(vvB, t0 + 5); stageK(t0 + 6, 0);
    WAIT_VM12(); SB0();
    compute(wbase + 2048, vvA); SB0();

    loadV(vvA, t0 + 6); stageK(t0 + 7, 1);
    WAIT_VM12(); SB0();
    compute(wbase + 4096, vvB); SB0();
  }
  // After loop: outstanding = K30,V30,K31 = 12.
  // t=30 (buf0, vvA): load V31 -> 16; vmcnt(8) completes K30,V30.
  loadV(vvB, 31);
  WAIT_VM8(); SB0();
  compute(wbase, vvA); SB0();
  // t=31 (buf1, vvB)
  WAIT_VM0(); SB0();
  compute(wbase + 2048, vvB);

  // per-wave l: sum across quads (lanes c, c+16, c+32, c+48)
  float lw[2];
#pragma unroll
  for (int nt = 0; nt < 2; nt++) {
    float l = l_acc[nt];
    l += __shfl_xor(l, 16);
    l += __shfl_xor(l, 32);
    lw[nt] = l;
  }

  // ---- merge 4 wave-partials (first barriers since loop start) ----
  __syncthreads();
  float* obuf = (float*)smem_raw;  // 2 x [32 q][72]
  float* lbuf = obuf + 4608;       // [4 waves][32 q]
  if (lane < 16) {
#pragma unroll
    for (int nt = 0; nt < 2; nt++) lbuf[wave * 32 + nt * 16 + c] = lw[nt];
  }
  if (wave < 2) {
    float* ob = obuf + wave * 2304;
#pragma unroll
    for (int mt = 0; mt < 4; mt++)
#pragma unroll
      for (int nt = 0; nt < 2; nt++)
        *(floatx4*)(ob + (nt * 16 + c) * 72 + mt * 16 + quad * 4) = o[mt][nt];
  }
  __syncthreads();
  if (wave >= 2) {
    float* ob = obuf + (wave - 2) * 2304;
#pragma unroll
    for (int mt = 0; mt < 4; mt++)
#pragma unroll
      for (int nt = 0; nt < 2; nt++) {
        float* a = ob + (nt * 16 + c) * 72 + mt * 16 + quad * 4;
        floatx4 cur = *(floatx4*)a;
        *(floatx4*)a = cur + o[mt][nt];
      }
  }
  __syncthreads();

  // out = O/l * mask, coalesced stores (256 threads: 8 cols x 32 rows each)
  const int row = tid >> 3, dg = (tid & 7) * 8;
  const float l = lbuf[row] + lbuf[32 + row] + lbuf[64 + row] + lbuf[96 + row];
  const float sc = mask[b * 4096 + q0 + row] / l;
  float* op = out + ((size_t)b * 4096 + q0 + row) * 64 + dg;
#pragma unroll
  for (int i = 0; i < 2; i++) {
    floatx4 a = *(const floatx4*)(obuf + row * 72 + dg + i * 4);
    floatx4 b2 = *(const floatx4*)(obuf + 2304 + row * 72 + dg + i * 4);
    *(floatx4*)(op + i * 4) = (a + b2) * sc;
  }
}

extern "C" void kernel_launch(void* const* d_in, const int* in_sizes, int n_in,
                              void* d_out, int out_size, void* d_ws, size_t ws_size,
                              hipStream_t stream) {
  const float* q = (const float*)d_in[0];
  const float* k = (const float*)d_in[1];
  const float* v = (const float*)d_in[2];
  const float* mask = (const float*)d_in[3];
  unsigned short* kb = (unsigned short*)d_ws;  // 4 MB
  unsigned short* vt = kb + 8 * 4096 * 64;     // 4 MB (needs ws >= 8 MB)
  prep_kv<<<512, 256, 0, stream>>>(k, v, kb, vt);
  attn<<<1024, 256, 0, stream>>>(q, kb, vt, mask, (float*)d_out);
}

// Round 5
// 129.835 us; speedup vs baseline: 27149.6920x; 1.0700x over previous
//
#include <hip/hip_runtime.h>

typedef __attribute__((ext_vector_type(8))) short short8;
typedef __attribute__((ext_vector_type(4))) float floatx4;
typedef __attribute__((ext_vector_type(4))) unsigned short ushortx4;
typedef __attribute__((ext_vector_type(8))) unsigned short ushortx8;
typedef unsigned int u32;
typedef __attribute__((ext_vector_type(2))) u32 u32x2;
typedef __attribute__((ext_vector_type(4))) u32 u32x4;

#define MFMA_K32(A, B, C) __builtin_amdgcn_mfma_f32_16x16x32_bf16(A, B, C, 0, 0, 0)

#if __has_builtin(__builtin_amdgcn_exp2f)
#define EXP2(x) __builtin_amdgcn_exp2f(x)
#else
#define EXP2(x) exp2f(x)
#endif

// gfx9 waitcnt imm: vmcnt[3:0] | expcnt<<4 | lgkmcnt<<8 | vmcnt[5:4]<<14 (exp/lgkm = no-wait)
#define WAIT_VM8() __builtin_amdgcn_s_waitcnt(0x0F78)  // keep 8 newest in flight
#define WAIT_VM4() __builtin_amdgcn_s_waitcnt(0x0F74)
#define WAIT_VM0() __builtin_amdgcn_s_waitcnt(0x0F70)
#define SB0() __builtin_amdgcn_sched_barrier(0)

__device__ __forceinline__ unsigned short f2bf(float f) {  // RNE
  u32 u = __builtin_bit_cast(u32, f);
  u += 0x7FFFu + ((u >> 16) & 1u);
  return (unsigned short)(u >> 16);
}
// async 16B/lane global->LDS: lds dst = wave-uniform base + lane*16
__device__ __forceinline__ void load_lds16(const void* g, void* l) {
  __builtin_amdgcn_global_load_lds((const __attribute__((address_space(1))) u32*)g,
                                   (__attribute__((address_space(3))) u32*)l, 16, 0, 0);
}

// Prep (512 blocks): K slab fp32->bf16 (plain [b][key][d]) + V 64-key tile ->
// vt[b][t*4+w][d][32key] bf16 (32-key wave windows, natural key order inside window).
__global__ __launch_bounds__(256) void prep_kv(
    const float* __restrict__ k, const float* __restrict__ v,
    unsigned short* __restrict__ kb, unsigned short* __restrict__ vt) {
  __shared__ float tileT[64 * 68];  // [d][key-in-64]
  const int blk = blockIdx.x, tid = threadIdx.x;
  size_t base = (size_t)blk * 4096 + tid * 4;
#pragma unroll
  for (int i = 0; i < 4; i++) {
    size_t off = base + (size_t)i * 1024;
    floatx4 f = *(const floatx4*)(k + off);
    ushortx4 h;
    h[0] = f2bf(f[0]); h[1] = f2bf(f[1]); h[2] = f2bf(f[2]); h[3] = f2bf(f[3]);
    *(ushortx4*)(kb + off) = h;
  }
  // V: block = (b, h) covering keys [h*64, h*64+64) -> windows (t=h>>1, w=2*(h&1)+s)
  const int b = blk >> 6, h = blk & 63;
  const int r = tid >> 2, c4 = (tid & 3) * 16;
  const float* vp = v + ((size_t)b * 4096 + h * 64 + r) * 64 + c4;
#pragma unroll
  for (int i = 0; i < 4; i++) {
    floatx4 f = *(const floatx4*)(vp + i * 4);
#pragma unroll
    for (int j = 0; j < 4; j++) tileT[(c4 + i * 4 + j) * 68 + r] = f[j];
  }
  __syncthreads();
  const int d = tid >> 2, g = tid & 3;
  unsigned short* vb = vt + (size_t)b * 262144 + ((h >> 1) * 4 + (h & 1) * 2) * 2048;
#pragma unroll
  for (int s = 0; s < 2; s++) {
    const float* src = tileT + d * 68 + s * 32 + g * 8;
    floatx4 f0 = *(const floatx4*)src;
    floatx4 f1 = *(const floatx4*)(src + 4);
    ushortx8 hh;
#pragma unroll
    for (int j = 0; j < 4; j++) { hh[j] = f2bf(f0[j]); hh[4 + j] = f2bf(f1[j]); }
    *(ushortx8*)(vb + s * 2048 + d * 32 + g * 8) = hh;
  }
}

// Attention: 512 blocks x 256 thr (4 waves) — the VERIFIED 47us round-0 structure
// (64-row Q-tiles: 536 MB K/V L2 traffic; 32-row halving doubles it — round-4 lesson),
// barrier-free, software-pipelined. NO min-waves hint (rounds 1-3: any cap below the
// ~200-reg demand spills 0.5-0.9 GB into the vmcnt loop). Occupancy stays 2 waves/SIMD;
// this round instead shortens the intra-wave critical path:
//   kf REGISTER PREFETCH: wait tightened vmcnt(12)->vmcnt(8) so K(t+1) is
//   LDS-complete during phase t; kf(t+1) ds_reads issue in phase t and their
//   ~150cy latency hides under exp/pack/PV instead of heading phase t+1.
//   Two kf sets (kfE/kfO) alternate by phase parity -> no register copies.
// K staged via DMA 2 tiles ahead (4 LDS bufs, row-PERMUTED so two 16-key QK tiles
// concatenate into one K32 PV B-frag); V register ping-pong 1 tile ahead.
// s_setprio(1) wraps MFMA clusters (waves drift out of phase -> role diversity).
// S^T=K*Q^T -> C-layout==PV B-frag layout -> P register-direct; l via ones-A K32.
__global__ __launch_bounds__(256) void attn(
    const float* __restrict__ q, const unsigned short* __restrict__ kb,
    const unsigned short* __restrict__ vt, const float* __restrict__ mask,
    float* __restrict__ out) {
  // loop: 4 waves x 4 K bufs x 2048 ushorts = 65536 B (wave-private)
  // epilogue reuses: obuf 2x[64][72] fp32 + lbuf [4][64] = 37888 B
  __shared__ __align__(16) char smem_raw[65536];
  unsigned short* smem = (unsigned short*)smem_raw;
  const int tid = threadIdx.x;
  const int wave = tid >> 6, lane = tid & 63;
  const int c = lane & 15, quad = lane >> 4;
  const int b = blockIdx.x & 7, qt = blockIdx.x >> 3;  // blk%8=batch -> per-XCD L2 locality
  const int q0 = qt * 64;

  const unsigned short* kB = kb + (size_t)b * (4096 * 64);
  const unsigned short* vtB = vt + (size_t)b * 262144;

  // Q B-frags (B[k=d=kc*32+quad*8+j][n=q=c]), loop-invariant; fold (1/8)*log2(e)
  const float qscale = 0.18033688011112042f;
  short8 qf[4][2];
#pragma unroll
  for (int nt = 0; nt < 4; nt++)
#pragma unroll
    for (int kc = 0; kc < 2; kc++) {
      const float* qp = q + ((size_t)b * 4096 + q0 + nt * 16 + c) * 64 + kc * 32 + quad * 8;
      floatx4 f0 = *(const floatx4*)qp;
      floatx4 f1 = *(const floatx4*)(qp + 4);
      short8 s;
#pragma unroll
      for (int j = 0; j < 4; j++) {
        s[j] = (short)f2bf(f0[j] * qscale);
        s[4 + j] = (short)f2bf(f1[j] * qscale);
      }
      qf[nt][kc] = s;
    }

  floatx4 o[4][4], o_l[4];  // O^T[d=mt*16+quad*4+r][q=nt*16+c]; o_l rows all equal l
#pragma unroll
  for (int mt = 0; mt < 4; mt++)
#pragma unroll
    for (int nt = 0; nt < 4; nt++) o[mt][nt] = (floatx4){0.f, 0.f, 0.f, 0.f};
#pragma unroll
  for (int nt = 0; nt < 4; nt++) o_l[nt] = (floatx4){0.f, 0.f, 0.f, 0.f};

  short8 ones8;
#pragma unroll
  for (int j = 0; j < 8; j++) ones8[j] = (short)0x3F80;

  const int r8 = lane >> 3, cs8 = lane & 7;
  const int klane = (r8 >> 2) * 8 + (r8 & 3);  // row-permutation: C row (quad,r) -> key quad*8+r
  unsigned short* wbase = smem + wave * 8192;  // 4 bufs x 2048
  const unsigned short* gK0 = kB + (size_t)(wave * 32 + klane) * 64 + (cs8 ^ r8) * 8;
  const unsigned short* gV0 = vtB + wave * 2048 + c * 32 + quad * 8;

  auto stageK = [&](int t, int buf) {  // 4KB: tileA (keys {q8+0..3}) | tileB ({q8+4..7})
    unsigned short* Kd = wbase + buf * 2048;
    const unsigned short* gk = gK0 + (size_t)t * 8192;
    load_lds16(gk, Kd);                   // tileA rows 0-7   (key off  0)
    load_lds16(gk + 16 * 64, Kd + 512);   // tileA rows 8-15  (key off 16)
    load_lds16(gk + 4 * 64, Kd + 1024);   // tileB rows 0-7   (key off  4)
    load_lds16(gk + 20 * 64, Kd + 1536);  // tileB rows 8-15  (key off 20)
  };
  auto loadV = [&](u32x4* vv, int t) {  // 4 x 1KB-coalesced register loads
    const unsigned short* gv = gV0 + (size_t)t * 8192;
#pragma unroll
    for (int mt = 0; mt < 4; mt++) vv[mt] = *(const u32x4*)(gv + mt * 512);
  };

  struct KF { short8 A[2]; short8 B[2]; };  // A[m=key][k=d]; phys slot = (kc*4+quad)^(c&7)
  auto readKF = [&](const unsigned short* Kbuf, KF& kf) {
#pragma unroll
    for (int kc = 0; kc < 2; kc++) {
      const int sl = ((kc * 4 + quad) ^ (c & 7)) * 8;
      kf.A[kc] = *(const short8*)(Kbuf + c * 64 + sl);
      kf.B[kc] = *(const short8*)(Kbuf + 1024 + c * 64 + sl);
    }
  };

  auto compute = [&](const KF& kf, const u32x4* vv) {
#pragma unroll
    for (int nt = 0; nt < 4; nt++) {
      floatx4 sA = (floatx4){0.f, 0.f, 0.f, 0.f}, sB = sA;
      __builtin_amdgcn_s_setprio(1);
      sA = MFMA_K32(kf.A[0], qf[nt][0], sA);
      sA = MFMA_K32(kf.A[1], qf[nt][1], sA);
      sB = MFMA_K32(kf.B[0], qf[nt][0], sB);
      sB = MFMA_K32(kf.B[1], qf[nt][1], sB);
      __builtin_amdgcn_s_setprio(0);
      // P^T[key=quad*8+j][q=nt*16+c]: A gives j=0..3, B gives j=4..7 (row-permuted staging)
      u32 a0 = __builtin_bit_cast(u32, EXP2(sA[0]));
      u32 a1 = __builtin_bit_cast(u32, EXP2(sA[1]));
      u32 a2 = __builtin_bit_cast(u32, EXP2(sA[2]));
      u32 a3 = __builtin_bit_cast(u32, EXP2(sA[3]));
      u32 b0 = __builtin_bit_cast(u32, EXP2(sB[0]));
      u32 b1 = __builtin_bit_cast(u32, EXP2(sB[1]));
      u32 b2 = __builtin_bit_cast(u32, EXP2(sB[2]));
      u32 b3 = __builtin_bit_cast(u32, EXP2(sB[3]));
      u32x4 pw = {__builtin_amdgcn_perm(a1, a0, 0x07060302u),
                  __builtin_amdgcn_perm(a3, a2, 0x07060302u),
                  __builtin_amdgcn_perm(b1, b0, 0x07060302u),
                  __builtin_amdgcn_perm(b3, b2, 0x07060302u)};
      short8 pf = __builtin_bit_cast(short8, pw);  // K32 B-frag: B[k=quad*8+j][n=c]
      __builtin_amdgcn_s_setprio(1);
#pragma unroll
      for (int mt = 0; mt < 4; mt++)
        o[mt][nt] = MFMA_K32(__builtin_bit_cast(short8, vv[mt]), pf, o[mt][nt]);
      o_l[nt] = MFMA_K32(ones8, pf, o_l[nt]);  // l rows: Sum_k P^T[k][q]
      __builtin_amdgcn_s_setprio(0);
    }
  };

  u32x4 vvA[4], vvB[4];
  KF kfE, kfO;  // even-phase / odd-phase kf sets (prefetched one phase ahead)
  stageK(0, 0);
  loadV(vvA, 0);
  stageK(1, 1);
  // outstanding: K0,V0,K1 = 12; vmcnt(8) completes K0 -> read kf0
  WAIT_VM8(); SB0();
  readKF(wbase, kfE);

  // Phase t invariant: outstanding before issues = V(t),K(t+1); issue V(t+1),K(t+2);
  // WAIT_VM8 completes V(t) (for this compute) AND K(t+1) (for the kf prefetch),
  // leaving V(t+1),K(t+2) in flight. readKF(t+1) latency hides under compute(t).
  // stageK(t+2) overwrites buf((t+2)&3): last ds_read from it completed 2 phases ago.
#pragma unroll 1
  for (int it = 0; it < 7; it++) {
    const int t0 = 4 * it;
    loadV(vvB, t0 + 1); stageK(t0 + 2, 2);
    WAIT_VM8(); SB0();
    readKF(wbase + 2048, kfO);
    compute(kfE, vvA); SB0();

    loadV(vvA, t0 + 2); stageK(t0 + 3, 3);
    WAIT_VM8(); SB0();
    readKF(wbase + 4096, kfE);
    compute(kfO, vvB); SB0();

    loadV(vvB, t0 + 3); stageK(t0 + 4, 0);
    WAIT_VM8(); SB0();
    readKF(wbase + 6144, kfO);
    compute(kfE, vvA); SB0();

    loadV(vvA, t0 + 4); stageK(t0 + 5, 1);
    WAIT_VM8(); SB0();
    readKF(wbase, kfE);
    compute(kfO, vvB); SB0();
  }
  // After it=6: phases 0..27 done; kfE holds kf(28); outstanding V28,K29.
  // Phase 28 (buf0 done, cur vvA):
  loadV(vvB, 29); stageK(30, 2);
  WAIT_VM8(); SB0();           // completes V28,K29
  readKF(wbase + 2048, kfO);   // kf(29)
  compute(kfE, vvA); SB0();
  // Phase 29:
  loadV(vvA, 30); stageK(31, 3);
  WAIT_VM8(); SB0();           // completes V29,K30
  readKF(wbase + 4096, kfE);   // kf(30)
  compute(kfO, vvB); SB0();
  // Phase 30:
  loadV(vvB, 31);
  WAIT_VM4(); SB0();           // outstanding V30,K31,V31 -> completes V30,K31
  readKF(wbase + 6144, kfO);   // kf(31)
  compute(kfE, vvA); SB0();
  // Phase 31:
  WAIT_VM0(); SB0();           // V31
  compute(kfO, vvB);

  // ---- merge 4 wave-partials (first barriers since loop start) ----
  __syncthreads();
  float* obuf = (float*)smem_raw;  // 2 x [64 q][72]
  float* lbuf = obuf + 9216;       // [4 waves][64 q]
  if (lane < 16) {
#pragma unroll
    for (int nt = 0; nt < 4; nt++) lbuf[wave * 64 + nt * 16 + c] = o_l[nt][0];
  }
  if (wave < 2) {
    float* ob = obuf + wave * 4608;
#pragma unroll
    for (int mt = 0; mt < 4; mt++)
#pragma unroll
      for (int nt = 0; nt < 4; nt++)
        *(floatx4*)(ob + (nt * 16 + c) * 72 + mt * 16 + quad * 4) = o[mt][nt];
  }
  __syncthreads();
  if (wave >= 2) {
    float* ob = obuf + (wave - 2) * 4608;
#pragma unroll
    for (int mt = 0; mt < 4; mt++)
#pragma unroll
      for (int nt = 0; nt < 4; nt++) {
        float* a = ob + (nt * 16 + c) * 72 + mt * 16 + quad * 4;
        floatx4 cur = *(floatx4*)a;
        *(floatx4*)a = cur + o[mt][nt];
      }
  }
  __syncthreads();

  // out = O/l * mask, coalesced float4 stores
  const int row = tid >> 2, dg = (tid & 3) * 16;
  const float l = lbuf[row] + lbuf[64 + row] + lbuf[128 + row] + lbuf[192 + row];
  const float sc = mask[b * 4096 + q0 + row] / l;
  float* op = out + ((size_t)b * 4096 + q0 + row) * 64 + dg;
#pragma unroll
  for (int i = 0; i < 4; i++) {
    floatx4 a = *(const floatx4*)(obuf + row * 72 + dg + i * 4);
    floatx4 b2 = *(const floatx4*)(obuf + 4608 + row * 72 + dg + i * 4);
    *(floatx4*)(op + i * 4) = (a + b2) * sc;
  }
}

extern "C" void kernel_launch(void* const* d_in, const int* in_sizes, int n_in,
                              void* d_out, int out_size, void* d_ws, size_t ws_size,
                              hipStream_t stream) {
  const float* q = (const float*)d_in[0];
  const float* k = (const float*)d_in[1];
  const float* v = (const float*)d_in[2];
  const float* mask = (const float*)d_in[3];
  unsigned short* kb = (unsigned short*)d_ws;  // 4 MB
  unsigned short* vt = kb + 8 * 4096 * 64;     // 4 MB (needs ws >= 8 MB)
  prep_kv<<<512, 256, 0, stream>>>(k, v, kb, vt);
  attn<<<512, 256, 0, stream>>>(q, kb, vt, mask, (float*)d_out);
}

// Round 6
// 123.364 us; speedup vs baseline: 28573.7943x; 1.0525x over previous
//
#include <hip/hip_runtime.h>

typedef __attribute__((ext_vector_type(8))) short short8;
typedef __attribute__((ext_vector_type(4))) float floatx4;
typedef __attribute__((ext_vector_type(4))) unsigned short ushortx4;
typedef __attribute__((ext_vector_type(8))) unsigned short ushortx8;
typedef unsigned int u32;
typedef __attribute__((ext_vector_type(2))) u32 u32x2;
typedef __attribute__((ext_vector_type(4))) u32 u32x4;

#define MFMA_K32(A, B, C) __builtin_amdgcn_mfma_f32_16x16x32_bf16(A, B, C, 0, 0, 0)

#if __has_builtin(__builtin_amdgcn_exp2f)
#define EXP2(x) __builtin_amdgcn_exp2f(x)
#else
#define EXP2(x) exp2f(x)
#endif

// gfx9 waitcnt imm: vmcnt[3:0] | expcnt<<4 | lgkmcnt<<8 | vmcnt[5:4]<<14 (exp/lgkm = no-wait)
#define WAIT_VM12() __builtin_amdgcn_s_waitcnt(0x0F7C)  // keep 12 newest in flight
#define WAIT_VM8() __builtin_amdgcn_s_waitcnt(0x0F78)
#define WAIT_VM4() __builtin_amdgcn_s_waitcnt(0x0F74)
#define WAIT_VM0() __builtin_amdgcn_s_waitcnt(0x0F70)
#define SB0() __builtin_amdgcn_sched_barrier(0)

__device__ __forceinline__ unsigned short f2bf(float f) {  // RNE
  u32 u = __builtin_bit_cast(u32, f);
  u += 0x7FFFu + ((u >> 16) & 1u);
  return (unsigned short)(u >> 16);
}
// async 16B/lane global->LDS: lds dst = wave-uniform base + lane*16
__device__ __forceinline__ void load_lds16(const void* g, void* l) {
  __builtin_amdgcn_global_load_lds((const __attribute__((address_space(1))) u32*)g,
                                   (__attribute__((address_space(3))) u32*)l, 16, 0, 0);
}

// Prep (512 blocks): K slab fp32->bf16 (plain [b][key][d]) + V 64-key tile ->
// vt[b][t*4+w][d][32key] bf16 (32-key wave windows, natural key order inside window).
__global__ __launch_bounds__(256) void prep_kv(
    const float* __restrict__ k, const float* __restrict__ v,
    unsigned short* __restrict__ kb, unsigned short* __restrict__ vt) {
  __shared__ float tileT[64 * 68];  // [d][key-in-64]
  const int blk = blockIdx.x, tid = threadIdx.x;
  size_t base = (size_t)blk * 4096 + tid * 4;
#pragma unroll
  for (int i = 0; i < 4; i++) {
    size_t off = base + (size_t)i * 1024;
    floatx4 f = *(const floatx4*)(k + off);
    ushortx4 h;
    h[0] = f2bf(f[0]); h[1] = f2bf(f[1]); h[2] = f2bf(f[2]); h[3] = f2bf(f[3]);
    *(ushortx4*)(kb + off) = h;
  }
  // V: block = (b, h) covering keys [h*64, h*64+64) -> windows (t=h>>1, w=2*(h&1)+s)
  const int b = blk >> 6, h = blk & 63;
  const int r = tid >> 2, c4 = (tid & 3) * 16;
  const float* vp = v + ((size_t)b * 4096 + h * 64 + r) * 64 + c4;
#pragma unroll
  for (int i = 0; i < 4; i++) {
    floatx4 f = *(const floatx4*)(vp + i * 4);
#pragma unroll
    for (int j = 0; j < 4; j++) tileT[(c4 + i * 4 + j) * 68 + r] = f[j];
  }
  __syncthreads();
  const int d = tid >> 2, g = tid & 3;
  unsigned short* vb = vt + (size_t)b * 262144 + ((h >> 1) * 4 + (h & 1) * 2) * 2048;
#pragma unroll
  for (int s = 0; s < 2; s++) {
    const float* src = tileT + d * 68 + s * 32 + g * 8;
    floatx4 f0 = *(const floatx4*)src;
    floatx4 f1 = *(const floatx4*)(src + 4);
    ushortx8 hh;
#pragma unroll
    for (int j = 0; j < 4; j++) { hh[j] = f2bf(f0[j]); hh[4 + j] = f2bf(f1[j]); }
    *(ushortx8*)(vb + s * 2048 + d * 32 + g * 8) = hh;
  }
}

// Attention: 512 blocks x 256 thr (4 waves), VERIFIED round-0 structure (64-row
// Q-tiles), barrier-free, software-pipelined. Single change vs round 0:
//   K staged THREE tiles ahead (same 4 LDS bufs; t consumed, t+1..t+3 staged).
//   Steady wait stays vmcnt(12) -- SAME in-flight count as round 0 (now
//   K(t+2),V(t+1),K(t+3)) -- but K(t+1) was issued 2 phases ago, so the wait now
//   also completes K(t+1), legalizing a kf(t+1) REGISTER PREFETCH whose
//   ds_read_b128 latency hides under phase t's exp/pack/PV. Round-5 lesson:
//   prefetch with only 2-ahead staging forces vmcnt(8) waits on a 1-phase-old
//   DMA and stalls (60us); depth must be restored first. No setprio (confound).
// NO min-waves hint (rounds 1-3: caps below ~200-reg demand spill 0.5-0.9 GB).
// Row-PERMUTED K staging: two 16-key QK tiles concatenate into one K32 PV B-frag.
// S^T=K*Q^T -> C-layout==PV B-frag layout -> P register-direct; l via ones-A K32.
__global__ __launch_bounds__(256) void attn(
    const float* __restrict__ q, const unsigned short* __restrict__ kb,
    const unsigned short* __restrict__ vt, const float* __restrict__ mask,
    float* __restrict__ out) {
  // loop: 4 waves x 4 K bufs x 2048 ushorts = 65536 B (wave-private)
  // epilogue reuses: obuf 2x[64][72] fp32 + lbuf [4][64] = 37888 B
  __shared__ __align__(16) char smem_raw[65536];
  unsigned short* smem = (unsigned short*)smem_raw;
  const int tid = threadIdx.x;
  const int wave = tid >> 6, lane = tid & 63;
  const int c = lane & 15, quad = lane >> 4;
  const int b = blockIdx.x & 7, qt = blockIdx.x >> 3;  // blk%8=batch -> per-XCD L2 locality
  const int q0 = qt * 64;

  const unsigned short* kB = kb + (size_t)b * (4096 * 64);
  const unsigned short* vtB = vt + (size_t)b * 262144;

  // Q B-frags (B[k=d=kc*32+quad*8+j][n=q=c]), loop-invariant; fold (1/8)*log2(e)
  const float qscale = 0.18033688011112042f;
  short8 qf[4][2];
#pragma unroll
  for (int nt = 0; nt < 4; nt++)
#pragma unroll
    for (int kc = 0; kc < 2; kc++) {
      const float* qp = q + ((size_t)b * 4096 + q0 + nt * 16 + c) * 64 + kc * 32 + quad * 8;
      floatx4 f0 = *(const floatx4*)qp;
      floatx4 f1 = *(const floatx4*)(qp + 4);
      short8 s;
#pragma unroll
      for (int j = 0; j < 4; j++) {
        s[j] = (short)f2bf(f0[j] * qscale);
        s[4 + j] = (short)f2bf(f1[j] * qscale);
      }
      qf[nt][kc] = s;
    }

  floatx4 o[4][4], o_l[4];  // O^T[d=mt*16+quad*4+r][q=nt*16+c]; o_l rows all equal l
#pragma unroll
  for (int mt = 0; mt < 4; mt++)
#pragma unroll
    for (int nt = 0; nt < 4; nt++) o[mt][nt] = (floatx4){0.f, 0.f, 0.f, 0.f};
#pragma unroll
  for (int nt = 0; nt < 4; nt++) o_l[nt] = (floatx4){0.f, 0.f, 0.f, 0.f};

  short8 ones8;
#pragma unroll
  for (int j = 0; j < 8; j++) ones8[j] = (short)0x3F80;

  const int r8 = lane >> 3, cs8 = lane & 7;
  const int klane = (r8 >> 2) * 8 + (r8 & 3);  // row-permutation: C row (quad,r) -> key quad*8+r
  unsigned short* wbase = smem + wave * 8192;  // 4 bufs x 2048
  const unsigned short* gK0 = kB + (size_t)(wave * 32 + klane) * 64 + (cs8 ^ r8) * 8;
  const unsigned short* gV0 = vtB + wave * 2048 + c * 32 + quad * 8;

  auto stageK = [&](int t, int buf) {  // 4KB: tileA (keys {q8+0..3}) | tileB ({q8+4..7})
    unsigned short* Kd = wbase + buf * 2048;
    const unsigned short* gk = gK0 + (size_t)t * 8192;
    load_lds16(gk, Kd);                   // tileA rows 0-7   (key off  0)
    load_lds16(gk + 16 * 64, Kd + 512);   // tileA rows 8-15  (key off 16)
    load_lds16(gk + 4 * 64, Kd + 1024);   // tileB rows 0-7   (key off  4)
    load_lds16(gk + 20 * 64, Kd + 1536);  // tileB rows 8-15  (key off 20)
  };
  auto loadV = [&](u32x4* vv, int t) {  // 4 x 1KB-coalesced register loads
    const unsigned short* gv = gV0 + (size_t)t * 8192;
#pragma unroll
    for (int mt = 0; mt < 4; mt++) vv[mt] = *(const u32x4*)(gv + mt * 512);
  };

  struct KF { short8 A[2]; short8 B[2]; };  // A[m=key][k=d]; phys slot = (kc*4+quad)^(c&7)
  auto readKF = [&](const unsigned short* Kbuf, KF& kf) {
#pragma unroll
    for (int kc = 0; kc < 2; kc++) {
      const int sl = ((kc * 4 + quad) ^ (c & 7)) * 8;
      kf.A[kc] = *(const short8*)(Kbuf + c * 64 + sl);
      kf.B[kc] = *(const short8*)(Kbuf + 1024 + c * 64 + sl);
    }
  };

  auto compute = [&](const KF& kf, const u32x4* vv) {
#pragma unroll
    for (int nt = 0; nt < 4; nt++) {
      floatx4 sA = (floatx4){0.f, 0.f, 0.f, 0.f}, sB = sA;
      sA = MFMA_K32(kf.A[0], qf[nt][0], sA);
      sA = MFMA_K32(kf.A[1], qf[nt][1], sA);
      sB = MFMA_K32(kf.B[0], qf[nt][0], sB);
      sB = MFMA_K32(kf.B[1], qf[nt][1], sB);
      // P^T[key=quad*8+j][q=nt*16+c]: A gives j=0..3, B gives j=4..7 (row-permuted staging)
      u32 a0 = __builtin_bit_cast(u32, EXP2(sA[0]));
      u32 a1 = __builtin_bit_cast(u32, EXP2(sA[1]));
      u32 a2 = __builtin_bit_cast(u32, EXP2(sA[2]));
      u32 a3 = __builtin_bit_cast(u32, EXP2(sA[3]));
      u32 b0 = __builtin_bit_cast(u32, EXP2(sB[0]));
      u32 b1 = __builtin_bit_cast(u32, EXP2(sB[1]));
      u32 b2 = __builtin_bit_cast(u32, EXP2(sB[2]));
      u32 b3 = __builtin_bit_cast(u32, EXP2(sB[3]));
      u32x4 pw = {__builtin_amdgcn_perm(a1, a0, 0x07060302u),
                  __builtin_amdgcn_perm(a3, a2, 0x07060302u),
                  __builtin_amdgcn_perm(b1, b0, 0x07060302u),
                  __builtin_amdgcn_perm(b3, b2, 0x07060302u)};
      short8 pf = __builtin_bit_cast(short8, pw);  // K32 B-frag: B[k=quad*8+j][n=c]
#pragma unroll
      for (int mt = 0; mt < 4; mt++)
        o[mt][nt] = MFMA_K32(__builtin_bit_cast(short8, vv[mt]), pf, o[mt][nt]);
      o_l[nt] = MFMA_K32(ones8, pf, o_l[nt]);  // l rows: Sum_k P^T[k][q]
    }
  };

  u32x4 vvA[4], vvB[4];
  KF kfE, kfO;  // even-phase / odd-phase kf sets (prefetched one phase ahead)
  stageK(0, 0);
  stageK(1, 1);
  loadV(vvA, 0);
  stageK(2, 2);
  // outstanding: K0,K1,V0,K2 = 16; vmcnt(12) completes K0 -> read kf(0)
  WAIT_VM12(); SB0();
  readKF(wbase, kfE);

  // Phase t invariant: outstanding before issues = K(t+1),V(t),K(t+2) [12].
  // Issue V(t+1), K(t+3) -> 20; vmcnt(12) completes the 8 oldest = K(t+1),V(t):
  // exactly what compute(t) [V(t)] and readKF(t+1) [K(t+1)] need; K(t+2),V(t+1),
  // K(t+3) stay in flight (same depth as round 0). readKF(t+1) ds_read latency
  // hides under compute(t). stageK(t+3) overwrites buf(t-1): its ds_reads were
  // consumed by compute(t-1)'s MFMAs (lgkmcnt) before this DMA issues.
#pragma unroll 1
  for (int it = 0; it < 7; it++) {
    const int t0 = 4 * it;
    loadV(vvB, t0 + 1); stageK(t0 + 3, 3);
    WAIT_VM12(); SB0();
    readKF(wbase + 2048, kfO);
    compute(kfE, vvA); SB0();

    loadV(vvA, t0 + 2); stageK(t0 + 4, 0);
    WAIT_VM12(); SB0();
    readKF(wbase + 4096, kfE);
    compute(kfO, vvB); SB0();

    loadV(vvB, t0 + 3); stageK(t0 + 5, 1);
    WAIT_VM12(); SB0();
    readKF(wbase + 6144, kfO);
    compute(kfE, vvA); SB0();

    loadV(vvA, t0 + 4); stageK(t0 + 6, 2);
    WAIT_VM12(); SB0();
    readKF(wbase, kfE);
    compute(kfO, vvB); SB0();
  }
  // After it=6 (phases 0..27): kfE=kf(28), vvA=V(28); outstanding K29,V28,K30 = 12.
  // Phase 28: issue V29,K31 -> 20; VM12 completes K29,V28.
  loadV(vvB, 29); stageK(31, 3);
  WAIT_VM12(); SB0();
  readKF(wbase + 2048, kfO);   // kf(29)
  compute(kfE, vvA); SB0();
  // Phase 29: outstanding K30,V29,K31 = 12; issue V30 -> 16; VM8 completes K30,V29.
  loadV(vvA, 30);
  WAIT_VM8(); SB0();
  readKF(wbase + 4096, kfE);   // kf(30)
  compute(kfO, vvB); SB0();
  // Phase 30: outstanding K31,V30 = 8; issue V31 -> 12; VM4 completes K31,V30.
  loadV(vvB, 31);
  WAIT_VM4(); SB0();
  readKF(wbase + 6144, kfO);   // kf(31)
  compute(kfE, vvA); SB0();
  // Phase 31: outstanding V31 = 4; VM0.
  WAIT_VM0(); SB0();
  compute(kfO, vvB);

  // ---- merge 4 wave-partials (first barriers since loop start) ----
  __syncthreads();
  float* obuf = (float*)smem_raw;  // 2 x [64 q][72]
  float* lbuf = obuf + 9216;       // [4 waves][64 q]
  if (lane < 16) {
#pragma unroll
    for (int nt = 0; nt < 4; nt++) lbuf[wave * 64 + nt * 16 + c] = o_l[nt][0];
  }
  if (wave < 2) {
    float* ob = obuf + wave * 4608;
#pragma unroll
    for (int mt = 0; mt < 4; mt++)
#pragma unroll
      for (int nt = 0; nt < 4; nt++)
        *(floatx4*)(ob + (nt * 16 + c) * 72 + mt * 16 + quad * 4) = o[mt][nt];
  }
  __syncthreads();
  if (wave >= 2) {
    float* ob = obuf + (wave - 2) * 4608;
#pragma unroll
    for (int mt = 0; mt < 4; mt++)
#pragma unroll
      for (int nt = 0; nt < 4; nt++) {
        float* a = ob + (nt * 16 + c) * 72 + mt * 16 + quad * 4;
        floatx4 cur = *(floatx4*)a;
        *(floatx4*)a = cur + o[mt][nt];
      }
  }
  __syncthreads();

  // out = O/l * mask, coalesced float4 stores
  const int row = tid >> 2, dg = (tid & 3) * 16;
  const float l = lbuf[row] + lbuf[64 + row] + lbuf[128 + row] + lbuf[192 + row];
  const float sc = mask[b * 4096 + q0 + row] / l;
  float* op = out + ((size_t)b * 4096 + q0 + row) * 64 + dg;
#pragma unroll
  for (int i = 0; i < 4; i++) {
    floatx4 a = *(const floatx4*)(obuf + row * 72 + dg + i * 4);
    floatx4 b2 = *(const floatx4*)(obuf + 4608 + row * 72 + dg + i * 4);
    *(floatx4*)(op + i * 4) = (a + b2) * sc;
  }
}

extern "C" void kernel_launch(void* const* d_in, const int* in_sizes, int n_in,
                              void* d_out, int out_size, void* d_ws, size_t ws_size,
                              hipStream_t stream) {
  const float* q = (const float*)d_in[0];
  const float* k = (const float*)d_in[1];
  const float* v = (const float*)d_in[2];
  const float* mask = (const float*)d_in[3];
  unsigned short* kb = (unsigned short*)d_ws;  // 4 MB
  unsigned short* vt = kb + 8 * 4096 * 64;     // 4 MB (needs ws >= 8 MB)
  prep_kv<<<512, 256, 0, stream>>>(k, v, kb, vt);
  attn<<<512, 256, 0, stream>>>(q, kb, vt, mask, (float*)d_out);
}